// Round 1
// baseline (394.201 us; speedup 1.0000x reference)
//
#include <hip/hip_runtime.h>
#include <hip/hip_bf16.h>

typedef unsigned short ushort_t;
typedef __attribute__((ext_vector_type(8))) short bf16x8;   // 8 bf16 = 4 VGPRs
typedef __attribute__((ext_vector_type(4))) float f32x4;    // 4 fp32 acc

#define MDIM 2048
#define NDIM 4096

__device__ __forceinline__ ushort_t to_bf16(float f) {
    __hip_bfloat16 h = __float2bfloat16(f);
    return *reinterpret_cast<ushort_t*>(&h);
}

// ---------------- prep: fp32 -> bf16 cast ----------------
__global__ void cast_bf16_kernel(const float* __restrict__ in, ushort_t* __restrict__ out, int n) {
    int i = blockIdx.x * blockDim.x + threadIdx.x;
    if (i < n) out[i] = to_bf16(in[i]);
}

// ---------------- prep: W[K][N] fp32 -> WT[N][K] bf16 ----------------
__global__ void transpose_cast_kernel(const float* __restrict__ W, ushort_t* __restrict__ WT,
                                      int K, int N) {
    __shared__ float tile[32][33];
    const int tx = threadIdx.x, ty = threadIdx.y;  // (32, 8)
    const int n0 = blockIdx.x * 32, k0 = blockIdx.y * 32;
#pragma unroll
    for (int r = 0; r < 4; ++r)
        tile[ty + r * 8][tx] = W[(size_t)(k0 + ty + r * 8) * N + n0 + tx];
    __syncthreads();
    const int t = ty * 32 + tx;
    const int nl = t >> 3;          // 0..31 : local n
    const int kc = (t & 7) * 4;     // 0..28 : k chunk of 4
    ushort4 o;
    o.x = to_bf16(tile[kc + 0][nl]);
    o.y = to_bf16(tile[kc + 1][nl]);
    o.z = to_bf16(tile[kc + 2][nl]);
    o.w = to_bf16(tile[kc + 3][nl]);
    *reinterpret_cast<ushort4*>(&WT[(size_t)(n0 + nl) * K + k0 + kc]) = o;
}

// ---------------- GEMM v2: phase-pipelined, counted-vmcnt (T3+T4+T2+T5) ----------------
// C[M][N] = act(A[M][K] @ BT[N][K]^T + bias)
// BM=128, BN=256, BK=64, 8 waves (2Mx4N), wave tile 64x64 (4x4 frags of 16x16x32).
// Grid (N/256, M/128) = 16x16 = 256 blocks = exactly 1 block/CU.
// LDS: 3 buffers x (A 16KB + B 32KB) = 144KB, staged via global_load_lds dwordx4
// (direct HBM->LDS, no VGPR roundtrip). Prefetch distance = 2 K-tiles; steady-state
// wait is s_waitcnt vmcnt(6) (one tile's 6 loads), never 0 in the main loop.
// Bank-conflict-free ds_read_b128 via chunk XOR swizzle: LDS slot s of row r holds
// global 16B-chunk s^(r&7); writes stay linear (global_load_lds requirement) by
// inverse-swizzling the per-lane GLOBAL source address (m173/m201 pattern).
// Each K-tile = 4 phases: {ds_read frags | 2 stage loads | s_barrier | lgkmcnt(0) |
// setprio(1) 8xMFMA setprio(0) | s_barrier}. MFMA order identical to previous
// kernel -> numerics unchanged.

#define GLD(gp, lp) __builtin_amdgcn_global_load_lds(                      \
        (const __attribute__((address_space(1))) void*)(gp),               \
        (__attribute__((address_space(3))) void*)(lp), 16, 0, 0)

#define MFMA(d, a, b) d = __builtin_amdgcn_mfma_f32_16x16x32_bf16(a, b, d, 0, 0, 0)

template <typename OutT, bool RELU>
__global__ __launch_bounds__(512, 2) void gemm_p8(const ushort_t* __restrict__ A,
                                                  const ushort_t* __restrict__ BT,
                                                  const float* __restrict__ bias,
                                                  OutT* __restrict__ C, int Kdim) {
    __shared__ __align__(16) ushort_t As[3][128 * 64];   // 48 KB
    __shared__ __align__(16) ushort_t Bs[3][256 * 64];   // 96 KB

    const int t = threadIdx.x;
    const int l = t & 63;
    const int w = t >> 6;          // wave 0..7
    const int l16 = l & 15;
    const int quad = l >> 4;
    const int wr = w >> 2;         // 0..1  (M)
    const int wc = w & 3;          // 0..3  (N)
    const int m0 = blockIdx.y * 128;
    const int n0 = blockIdx.x * 256;

    f32x4 acc[4][4];
#pragma unroll
    for (int i = 0; i < 4; ++i)
#pragma unroll
        for (int j = 0; j < 4; ++j) acc[i][j] = (f32x4){0.f, 0.f, 0.f, 0.f};

    // --- staging addressing ---
    // wave w stages rows [g*64 + w*8, +8) of each 64-row group g; lane l -> row +l>>3,
    // LDS chunk l&7 (linear dest = base + l*16B). Source chunk is inverse-swizzled.
    const int srow = w * 8 + (l >> 3);
    const int scol = ((l & 7) ^ (l >> 3)) * 8;   // swizzled 16B chunk within the K-tile
    const ushort_t* gA0 = A  + (size_t)(m0 + srow) * Kdim + scol;
    const ushort_t* gA1 = A  + (size_t)(m0 + 64 + srow) * Kdim + scol;
    const ushort_t* gB0 = BT + (size_t)(n0 + srow) * Kdim + scol;
    const ushort_t* gB1 = BT + (size_t)(n0 + 64 + srow) * Kdim + scol;
    const ushort_t* gB2 = BT + (size_t)(n0 + 128 + srow) * Kdim + scol;
    const ushort_t* gB3 = BT + (size_t)(n0 + 192 + srow) * Kdim + scol;
    const int ldsW = w * 8 * 64;   // wave-uniform element offset of this wave's 8 rows

    // fragment reads: row = (wtile + i*16 + l16), chunk slot = (kk*4+quad)^(row&7)
    const int swz = l16 & 7;       // == row&7 for all our fragment rows
#define LDA_(buf, i, kk) (*(const bf16x8*)&As[buf][(wr * 64 + (i) * 16 + l16) * 64 + ((((kk) * 4 + quad) ^ swz) * 8)])
#define LDB_(buf, j, kk) (*(const bf16x8*)&Bs[buf][(wc * 64 + (j) * 16 + l16) * 64 + ((((kk) * 4 + quad) ^ swz) * 8)])

#define STAGE_TILE(buf, koff) do {                      \
        GLD(gA0 + (koff), &As[buf][ldsW]);              \
        GLD(gA1 + (koff), &As[buf][ldsW + 64 * 64]);    \
        GLD(gB0 + (koff), &Bs[buf][ldsW]);              \
        GLD(gB1 + (koff), &Bs[buf][ldsW + 64 * 64]);    \
        GLD(gB2 + (koff), &Bs[buf][ldsW + 128 * 64]);   \
        GLD(gB3 + (koff), &Bs[buf][ldsW + 192 * 64]);   \
    } while (0)

#define PHASE_BEGIN()                                       \
        __builtin_amdgcn_s_barrier();                       \
        asm volatile("s_waitcnt lgkmcnt(0)" ::: "memory");  \
        __builtin_amdgcn_s_setprio(1)
#define PHASE_END()                                         \
        __builtin_amdgcn_s_setprio(0);                      \
        __builtin_amdgcn_s_barrier()

#define MFMA8(r0, r1, A0, A1)                                      \
        MFMA(acc[r0][0], A0, b0); MFMA(acc[r0][1], A0, b1);        \
        MFMA(acc[r0][2], A0, b2); MFMA(acc[r0][3], A0, b3);        \
        MFMA(acc[r1][0], A1, b0); MFMA(acc[r1][1], A1, b1);        \
        MFMA(acc[r1][2], A1, b2); MFMA(acc[r1][3], A1, b3)

    const int nt = Kdim >> 6;      // K-tiles of 64 (nt >= 2 for K in {256, 4096})

    // prologue: stage tiles 0 and 1; wait tile 0 (6 newer outstanding), sync.
    STAGE_TILE(0, 0);
    STAGE_TILE(1, 64);
    asm volatile("s_waitcnt vmcnt(6)" ::: "memory");
    __builtin_amdgcn_s_barrier();

    for (int tt = 0; tt < nt; ++tt) {
        const int buf = tt % 3;
        const int nb = (tt + 2) % 3;
        const int koff = (tt + 2) << 6;
        const bool more = (tt + 2) < nt;

        bf16x8 a0, a1, b0, b1, b2, b3;

        // ---- P0: kk=0, rows 0,1 ; stage A of tile tt+2 ----
        a0 = LDA_(buf, 0, 0); a1 = LDA_(buf, 1, 0);
        b0 = LDB_(buf, 0, 0); b1 = LDB_(buf, 1, 0);
        b2 = LDB_(buf, 2, 0); b3 = LDB_(buf, 3, 0);
        if (more) {
            GLD(gA0 + koff, &As[nb][ldsW]);
            GLD(gA1 + koff, &As[nb][ldsW + 64 * 64]);
        }
        PHASE_BEGIN();
        MFMA8(0, 1, a0, a1);
        PHASE_END();

        // ---- P1: kk=0, rows 2,3 (B frags reused) ; stage B0,B1 ----
        a0 = LDA_(buf, 2, 0); a1 = LDA_(buf, 3, 0);
        if (more) {
            GLD(gB0 + koff, &Bs[nb][ldsW]);
            GLD(gB1 + koff, &Bs[nb][ldsW + 64 * 64]);
        }
        PHASE_BEGIN();
        MFMA8(2, 3, a0, a1);
        PHASE_END();

        // ---- P2: kk=1, rows 0,1 ; stage B2,B3 ----
        a0 = LDA_(buf, 0, 1); a1 = LDA_(buf, 1, 1);
        b0 = LDB_(buf, 0, 1); b1 = LDB_(buf, 1, 1);
        b2 = LDB_(buf, 2, 1); b3 = LDB_(buf, 3, 1);
        if (more) {
            GLD(gB2 + koff, &Bs[nb][ldsW + 128 * 64]);
            GLD(gB3 + koff, &Bs[nb][ldsW + 192 * 64]);
        }
        PHASE_BEGIN();
        MFMA8(0, 1, a0, a1);
        PHASE_END();

        // ---- P3: kk=1, rows 2,3 ; end-of-tile counted wait ----
        a0 = LDA_(buf, 2, 1); a1 = LDA_(buf, 3, 1);
        PHASE_BEGIN();
        MFMA8(2, 3, a0, a1);
        __builtin_amdgcn_s_setprio(0);
        if (tt + 1 < nt) {
            // next iter reads buf (tt+1)%3: its 6 loads must be done. Newer in
            // flight = tile tt+2's 6 iff staged this iter -> vmcnt(6), else drain.
            if (more) asm volatile("s_waitcnt vmcnt(6)" ::: "memory");
            else      asm volatile("s_waitcnt vmcnt(0)" ::: "memory");
        }
        __builtin_amdgcn_s_barrier();
    }

    // epilogue: C/D layout col=lane&15, row=quad*4+reg (unchanged mapping)
#pragma unroll
    for (int i = 0; i < 4; ++i) {
#pragma unroll
        for (int r = 0; r < 4; ++r) {
            const int grow = m0 + wr * 64 + i * 16 + quad * 4 + r;
#pragma unroll
            for (int j = 0; j < 4; ++j) {
                const int gcol = n0 + wc * 64 + j * 16 + l16;
                float v = acc[i][j][r] + bias[gcol];
                if (RELU) v = fmaxf(v, 0.0f);
                if constexpr (sizeof(OutT) == 2) {
                    C[(size_t)grow * NDIM + gcol] = to_bf16(v);
                } else {
                    C[(size_t)grow * NDIM + gcol] = v;
                }
            }
        }
    }
}

// ---------------- Sinkhorn, factored: P = diag(a) K diag(b) ----------------
// (unchanged from previous round — register-resident K, readlane broadcast)
__device__ __forceinline__ float rdl(float v, int l) {
    return __uint_as_float(__builtin_amdgcn_readlane(__float_as_uint(v), l));
}

__global__ __launch_bounds__(64) void sinkhorn_kernel(float* __restrict__ PM) {
    __shared__ __align__(16) float T[64 * 65];  // one-time transpose staging
    const int l = threadIdx.x;
    float* base = PM + (size_t)blockIdx.x * 4096;

    float Kcol[64];  // Kcol[r] = K[r][l]  (column l)
    float Krow[64];  // Krow[c] = K[l][c]  (row l)
#pragma unroll
    for (int r = 0; r < 64; ++r)
        Kcol[r] = __expf(-base[r * 64 + l]);
#pragma unroll
    for (int r = 0; r < 64; ++r)
        T[r * 65 + l] = Kcol[r];
    __syncthreads();
#pragma unroll
    for (int c = 0; c < 64; ++c)
        Krow[c] = T[l * 65 + c];

    float a = 0.0f, b = 1.0f;
    for (int it = 0; it < 1000; ++it) {
        float t1 = 0.0f;  // (K b)_row=l
#pragma unroll
        for (int c = 0; c < 64; ++c)
            t1 = fmaf(Krow[c], rdl(b, c), t1);
        a = 0.015625f / t1;  // r = 1/64

        float t2 = 0.0f;  // (K^T a)_col=l
#pragma unroll
        for (int r = 0; r < 64; ++r)
            t2 = fmaf(Kcol[r], rdl(a, r), t2);
        const float err = fabsf(b * t2 - 0.015625f);
        if (__ballot(err > 1e-6f) == 0ull) break;
        b = 0.015625f / t2;
    }

#pragma unroll
    for (int r = 0; r < 64; ++r)
        base[r * 64 + l] = rdl(a, r) * Kcol[r] * b;
}

extern "C" void kernel_launch(void* const* d_in, const int* in_sizes, int n_in,
                              void* d_out, int out_size, void* d_ws, size_t ws_size,
                              hipStream_t stream) {
    const float* z  = (const float*)d_in[0];
    const float* W1 = (const float*)d_in[1];
    const float* b1 = (const float*)d_in[2];
    const float* W2 = (const float*)d_in[3];
    const float* b2 = (const float*)d_in[4];
    const float* W3 = (const float*)d_in[5];
    const float* b3 = (const float*)d_in[6];
    float* out = (float*)d_out;
    char* ws = (char*)d_ws;

    // workspace layout (bytes)
    ushort_t* W2T = (ushort_t*)(ws + 0);                       // 4096*4096*2 = 32 MB
    ushort_t* W3T = (ushort_t*)(ws + (size_t)33554432);        // 32 MB
    ushort_t* C1b = (ushort_t*)(ws + (size_t)67108864);        // 2048*4096*2 = 16 MB
    ushort_t* C2b = (ushort_t*)(ws + (size_t)83886080);        // 16 MB
    ushort_t* Zb  = (ushort_t*)(ws + (size_t)100663296);       // 2048*256*2 = 1 MB
    ushort_t* W1T = (ushort_t*)(ws + (size_t)101711872);       // 4096*256*2 = 2 MB

    // prep
    cast_bf16_kernel<<<2048, 256, 0, stream>>>(z, Zb, MDIM * 256);
    transpose_cast_kernel<<<dim3(128, 8), dim3(32, 8), 0, stream>>>(W1, W1T, 256, 4096);
    transpose_cast_kernel<<<dim3(128, 128), dim3(32, 8), 0, stream>>>(W2, W2T, 4096, 4096);
    transpose_cast_kernel<<<dim3(128, 128), dim3(32, 8), 0, stream>>>(W3, W3T, 4096, 4096);

    // 3-layer MLP (bf16 MFMA, fp32 accum); layer 3 writes fp32 cost matrix into d_out
    gemm_p8<ushort_t, true><<<dim3(NDIM / 256, MDIM / 128), 512, 0, stream>>>(Zb, W1T, b1, C1b, 256);
    gemm_p8<ushort_t, true><<<dim3(NDIM / 256, MDIM / 128), 512, 0, stream>>>(C1b, W2T, b2, C2b, 4096);
    gemm_p8<float, false><<<dim3(NDIM / 256, MDIM / 128), 512, 0, stream>>>(C2b, W3T, b3, out, 4096);

    // Sinkhorn in-place on d_out (one wave per matrix, register-resident K)
    sinkhorn_kernel<<<2048, 64, 0, stream>>>(out);
}

// Round 2
// 360.070 us; speedup vs baseline: 1.0948x; 1.0948x over previous
//
#include <hip/hip_runtime.h>
#include <hip/hip_bf16.h>

typedef unsigned short ushort_t;
typedef __attribute__((ext_vector_type(8))) short bf16x8;   // 8 bf16 = 4 VGPRs
typedef __attribute__((ext_vector_type(4))) float f32x4;    // 4 fp32 acc

#define MDIM 2048
#define NDIM 4096

__device__ __forceinline__ ushort_t to_bf16(float f) {
    __hip_bfloat16 h = __float2bfloat16(f);
    return *reinterpret_cast<ushort_t*>(&h);
}

// ---------------- prep: fp32 -> bf16 cast ----------------
__global__ void cast_bf16_kernel(const float* __restrict__ in, ushort_t* __restrict__ out, int n) {
    int i = blockIdx.x * blockDim.x + threadIdx.x;
    if (i < n) out[i] = to_bf16(in[i]);
}

// ---------------- prep: W[K][N] fp32 -> WT[N][K] bf16 ----------------
__global__ void transpose_cast_kernel(const float* __restrict__ W, ushort_t* __restrict__ WT,
                                      int K, int N) {
    __shared__ float tile[32][33];
    const int tx = threadIdx.x, ty = threadIdx.y;  // (32, 8)
    const int n0 = blockIdx.x * 32, k0 = blockIdx.y * 32;
#pragma unroll
    for (int r = 0; r < 4; ++r)
        tile[ty + r * 8][tx] = W[(size_t)(k0 + ty + r * 8) * N + n0 + tx];
    __syncthreads();
    const int t = ty * 32 + tx;
    const int nl = t >> 3;          // 0..31 : local n
    const int kc = (t & 7) * 4;     // 0..28 : k chunk of 4
    ushort4 o;
    o.x = to_bf16(tile[kc + 0][nl]);
    o.y = to_bf16(tile[kc + 1][nl]);
    o.z = to_bf16(tile[kc + 2][nl]);
    o.w = to_bf16(tile[kc + 3][nl]);
    *reinterpret_cast<ushort4*>(&WT[(size_t)(n0 + nl) * K + k0 + kc]) = o;
}

// ---------------- GEMM v3: 2 balanced phases per K-tile ----------------
// C[M][N] = act(A[M][K] @ BT[N][K]^T + bias)
// BM=128, BN=256, BK=64, 8 waves (2Mx4N), wave tile 64x64 (4x4 frags of 16x16x32).
// Grid (N/256, M/128) = 16x16 = 256 blocks = 1 block/CU.
// v2 post-mortem: 4 phases x 8 MFMA gave identical 102us to the old 2-barrier
// loop - per-phase fixed cost (~650cyc: 2 barriers + lgkm drain + reconverge)
// swamped the 310cyc MFMA region. v3 matches m201's verified ratio: 2 phases
// per K-tile, each {8 ds_read_b128 + 3 global_load_lds | bar | lgkm(0) |
// setprio(1) 16 MFMA setprio(0) | bar}. MFMA region/CU = 620cyc vs LDS region
// ~620-770cyc -> cross-wave overlap can cover the fixed costs.
// LDS: 3 buffers, prefetch distance 2, steady-state wait vmcnt(6) once per
// tile (never 0 in main loop). Chunk-XOR swizzle (conflict-free, verified 0
// SQ_LDS_BANK_CONFLICT in v2). MFMA order per-acc unchanged -> numerics
// bitwise identical to v1/v2.

#define GLD(gp, lp) __builtin_amdgcn_global_load_lds(                      \
        (const __attribute__((address_space(1))) void*)(gp),               \
        (__attribute__((address_space(3))) void*)(lp), 16, 0, 0)

#define MFMA(d, a, b) d = __builtin_amdgcn_mfma_f32_16x16x32_bf16(a, b, d, 0, 0, 0)

template <typename OutT, bool RELU>
__global__ __launch_bounds__(512, 2) void gemm_p8(const ushort_t* __restrict__ A,
                                                  const ushort_t* __restrict__ BT,
                                                  const float* __restrict__ bias,
                                                  OutT* __restrict__ C, int Kdim) {
    __shared__ __align__(16) ushort_t As[3][128 * 64];   // 48 KB
    __shared__ __align__(16) ushort_t Bs[3][256 * 64];   // 96 KB

    const int t = threadIdx.x;
    const int l = t & 63;
    const int w = t >> 6;          // wave 0..7
    const int l16 = l & 15;
    const int quad = l >> 4;
    const int wr = w >> 2;         // 0..1  (M)
    const int wc = w & 3;          // 0..3  (N)
    const int m0 = blockIdx.y * 128;
    const int n0 = blockIdx.x * 256;

    f32x4 acc[4][4];
#pragma unroll
    for (int i = 0; i < 4; ++i)
#pragma unroll
        for (int j = 0; j < 4; ++j) acc[i][j] = (f32x4){0.f, 0.f, 0.f, 0.f};

    // --- staging addressing ---
    // wave w stages rows [g*64 + w*8, +8) of each 64-row group g; lane l -> row +l>>3,
    // LDS chunk l&7 (linear dest = base + l*16B). Source chunk is inverse-swizzled.
    const int srow = w * 8 + (l >> 3);
    const int scol = ((l & 7) ^ (l >> 3)) * 8;   // swizzled 16B chunk within the K-tile
    const ushort_t* gA0 = A  + (size_t)(m0 + srow) * Kdim + scol;
    const ushort_t* gA1 = A  + (size_t)(m0 + 64 + srow) * Kdim + scol;
    const ushort_t* gB0 = BT + (size_t)(n0 + srow) * Kdim + scol;
    const ushort_t* gB1 = BT + (size_t)(n0 + 64 + srow) * Kdim + scol;
    const ushort_t* gB2 = BT + (size_t)(n0 + 128 + srow) * Kdim + scol;
    const ushort_t* gB3 = BT + (size_t)(n0 + 192 + srow) * Kdim + scol;
    const int ldsW = w * 8 * 64;   // wave-uniform element offset of this wave's 8 rows

    // fragment reads: row = (wtile + i*16 + l16), chunk slot = (kk*4+quad)^(row&7)
    const int swz = l16 & 7;       // == row&7 for all our fragment rows
#define LDA_(buf, i, kk) (*(const bf16x8*)&As[buf][(wr * 64 + (i) * 16 + l16) * 64 + ((((kk) * 4 + quad) ^ swz) * 8)])
#define LDB_(buf, j, kk) (*(const bf16x8*)&Bs[buf][(wc * 64 + (j) * 16 + l16) * 64 + ((((kk) * 4 + quad) ^ swz) * 8)])

#define STAGE_TILE(buf, koff) do {                      \
        GLD(gA0 + (koff), &As[buf][ldsW]);              \
        GLD(gA1 + (koff), &As[buf][ldsW + 64 * 64]);    \
        GLD(gB0 + (koff), &Bs[buf][ldsW]);              \
        GLD(gB1 + (koff), &Bs[buf][ldsW + 64 * 64]);    \
        GLD(gB2 + (koff), &Bs[buf][ldsW + 128 * 64]);   \
        GLD(gB3 + (koff), &Bs[buf][ldsW + 192 * 64]);   \
    } while (0)

#define PHASE_BEGIN()                                       \
        __builtin_amdgcn_s_barrier();                       \
        asm volatile("s_waitcnt lgkmcnt(0)" ::: "memory");  \
        __builtin_amdgcn_s_setprio(1)
#define PHASE_END()                                         \
        __builtin_amdgcn_s_setprio(0);                      \
        __builtin_amdgcn_s_barrier()

    // 16 MFMAs: full 4x4 acc update at one kk (i-major, j-minor -> per-acc
    // order identical to previous versions)
#define MFMA16()                                                   \
        MFMA(acc[0][0], a0, b0); MFMA(acc[0][1], a0, b1);          \
        MFMA(acc[0][2], a0, b2); MFMA(acc[0][3], a0, b3);          \
        MFMA(acc[1][0], a1, b0); MFMA(acc[1][1], a1, b1);          \
        MFMA(acc[1][2], a1, b2); MFMA(acc[1][3], a1, b3);          \
        MFMA(acc[2][0], a2, b0); MFMA(acc[2][1], a2, b1);          \
        MFMA(acc[2][2], a2, b2); MFMA(acc[2][3], a2, b3);          \
        MFMA(acc[3][0], a3, b0); MFMA(acc[3][1], a3, b1);          \
        MFMA(acc[3][2], a3, b2); MFMA(acc[3][3], a3, b3)

    const int nt = Kdim >> 6;      // K-tiles of 64 (nt >= 2 for K in {256, 4096})

    // prologue: stage tiles 0 and 1; wait tile 0 (6 newer outstanding), sync.
    STAGE_TILE(0, 0);
    STAGE_TILE(1, 64);
    asm volatile("s_waitcnt vmcnt(6)" ::: "memory");
    __builtin_amdgcn_s_barrier();

    for (int tt = 0; tt < nt; ++tt) {
        const int buf = tt % 3;
        const int nb = (tt + 2) % 3;
        const int koff = (tt + 2) << 6;
        const bool more = (tt + 2) < nt;

        bf16x8 a0, a1, a2, a3, b0, b1, b2, b3;

        // ---- Phase A: kk=0, all 16 MFMA ; stage A0,A1,B0 of tile tt+2 ----
        a0 = LDA_(buf, 0, 0); a1 = LDA_(buf, 1, 0);
        a2 = LDA_(buf, 2, 0); a3 = LDA_(buf, 3, 0);
        b0 = LDB_(buf, 0, 0); b1 = LDB_(buf, 1, 0);
        b2 = LDB_(buf, 2, 0); b3 = LDB_(buf, 3, 0);
        if (more) {
            GLD(gA0 + koff, &As[nb][ldsW]);
            GLD(gA1 + koff, &As[nb][ldsW + 64 * 64]);
            GLD(gB0 + koff, &Bs[nb][ldsW]);
        }
        PHASE_BEGIN();
        MFMA16();
        PHASE_END();

        // ---- Phase B: kk=1, all 16 MFMA ; stage B1,B2,B3 ; counted wait ----
        a0 = LDA_(buf, 0, 1); a1 = LDA_(buf, 1, 1);
        a2 = LDA_(buf, 2, 1); a3 = LDA_(buf, 3, 1);
        b0 = LDB_(buf, 0, 1); b1 = LDB_(buf, 1, 1);
        b2 = LDB_(buf, 2, 1); b3 = LDB_(buf, 3, 1);
        if (more) {
            GLD(gB1 + koff, &Bs[nb][ldsW + 64 * 64]);
            GLD(gB2 + koff, &Bs[nb][ldsW + 128 * 64]);
            GLD(gB3 + koff, &Bs[nb][ldsW + 192 * 64]);
        }
        PHASE_BEGIN();
        MFMA16();
        __builtin_amdgcn_s_setprio(0);
        if (tt + 1 < nt) {
            // next iter reads buf (tt+1)%3: its 6 loads must be done. Newer in
            // flight = tile tt+2's 6 iff staged this iter -> vmcnt(6), else drain.
            if (more) asm volatile("s_waitcnt vmcnt(6)" ::: "memory");
            else      asm volatile("s_waitcnt vmcnt(0)" ::: "memory");
        }
        __builtin_amdgcn_s_barrier();
    }

    // epilogue: C/D layout col=lane&15, row=quad*4+reg (unchanged mapping)
#pragma unroll
    for (int i = 0; i < 4; ++i) {
#pragma unroll
        for (int r = 0; r < 4; ++r) {
            const int grow = m0 + wr * 64 + i * 16 + quad * 4 + r;
#pragma unroll
            for (int j = 0; j < 4; ++j) {
                const int gcol = n0 + wc * 64 + j * 16 + l16;
                float v = acc[i][j][r] + bias[gcol];
                if (RELU) v = fmaxf(v, 0.0f);
                if constexpr (sizeof(OutT) == 2) {
                    C[(size_t)grow * NDIM + gcol] = to_bf16(v);
                } else {
                    C[(size_t)grow * NDIM + gcol] = v;
                }
            }
        }
    }
}

// ---------------- Sinkhorn, factored: P = diag(a) K diag(b) ----------------
// (unchanged — register-resident K, readlane broadcast)
__device__ __forceinline__ float rdl(float v, int l) {
    return __uint_as_float(__builtin_amdgcn_readlane(__float_as_uint(v), l));
}

__global__ __launch_bounds__(64) void sinkhorn_kernel(float* __restrict__ PM) {
    __shared__ __align__(16) float T[64 * 65];  // one-time transpose staging
    const int l = threadIdx.x;
    float* base = PM + (size_t)blockIdx.x * 4096;

    float Kcol[64];  // Kcol[r] = K[r][l]  (column l)
    float Krow[64];  // Krow[c] = K[l][c]  (row l)
#pragma unroll
    for (int r = 0; r < 64; ++r)
        Kcol[r] = __expf(-base[r * 64 + l]);
#pragma unroll
    for (int r = 0; r < 64; ++r)
        T[r * 65 + l] = Kcol[r];
    __syncthreads();
#pragma unroll
    for (int c = 0; c < 64; ++c)
        Krow[c] = T[l * 65 + c];

    float a = 0.0f, b = 1.0f;
    for (int it = 0; it < 1000; ++it) {
        float t1 = 0.0f;  // (K b)_row=l
#pragma unroll
        for (int c = 0; c < 64; ++c)
            t1 = fmaf(Krow[c], rdl(b, c), t1);
        a = 0.015625f / t1;  // r = 1/64

        float t2 = 0.0f;  // (K^T a)_col=l
#pragma unroll
        for (int r = 0; r < 64; ++r)
            t2 = fmaf(Kcol[r], rdl(a, r), t2);
        const float err = fabsf(b * t2 - 0.015625f);
        if (__ballot(err > 1e-6f) == 0ull) break;
        b = 0.015625f / t2;
    }

#pragma unroll
    for (int r = 0; r < 64; ++r)
        base[r * 64 + l] = rdl(a, r) * Kcol[r] * b;
}

extern "C" void kernel_launch(void* const* d_in, const int* in_sizes, int n_in,
                              void* d_out, int out_size, void* d_ws, size_t ws_size,
                              hipStream_t stream) {
    const float* z  = (const float*)d_in[0];
    const float* W1 = (const float*)d_in[1];
    const float* b1 = (const float*)d_in[2];
    const float* W2 = (const float*)d_in[3];
    const float* b2 = (const float*)d_in[4];
    const float* W3 = (const float*)d_in[5];
    const float* b3 = (const float*)d_in[6];
    float* out = (float*)d_out;
    char* ws = (char*)d_ws;

    // workspace layout (bytes)
    ushort_t* W2T = (ushort_t*)(ws + 0);                       // 4096*4096*2 = 32 MB
    ushort_t* W3T = (ushort_t*)(ws + (size_t)33554432);        // 32 MB
    ushort_t* C1b = (ushort_t*)(ws + (size_t)67108864);        // 2048*4096*2 = 16 MB
    ushort_t* C2b = (ushort_t*)(ws + (size_t)83886080);        // 16 MB
    ushort_t* Zb  = (ushort_t*)(ws + (size_t)100663296);       // 2048*256*2 = 1 MB
    ushort_t* W1T = (ushort_t*)(ws + (size_t)101711872);       // 4096*256*2 = 2 MB

    // prep
    cast_bf16_kernel<<<2048, 256, 0, stream>>>(z, Zb, MDIM * 256);
    transpose_cast_kernel<<<dim3(128, 8), dim3(32, 8), 0, stream>>>(W1, W1T, 256, 4096);
    transpose_cast_kernel<<<dim3(128, 128), dim3(32, 8), 0, stream>>>(W2, W2T, 4096, 4096);
    transpose_cast_kernel<<<dim3(128, 128), dim3(32, 8), 0, stream>>>(W3, W3T, 4096, 4096);

    // 3-layer MLP (bf16 MFMA, fp32 accum); layer 3 writes fp32 cost matrix into d_out
    gemm_p8<ushort_t, true><<<dim3(NDIM / 256, MDIM / 128), 512, 0, stream>>>(Zb, W1T, b1, C1b, 256);
    gemm_p8<ushort_t, true><<<dim3(NDIM / 256, MDIM / 128), 512, 0, stream>>>(C1b, W2T, b2, C2b, 4096);
    gemm_p8<float, false><<<dim3(NDIM / 256, MDIM / 128), 512, 0, stream>>>(C2b, W3T, b3, out, 4096);

    // Sinkhorn in-place on d_out (one wave per matrix, register-resident K)
    sinkhorn_kernel<<<2048, 64, 0, stream>>>(out);
}

// Round 3
// 332.997 us; speedup vs baseline: 1.1838x; 1.0813x over previous
//
#include <hip/hip_runtime.h>
#include <hip/hip_bf16.h>

typedef unsigned short ushort_t;
typedef __attribute__((ext_vector_type(8))) short bf16x8;   // 8 bf16 = 4 VGPRs
typedef __attribute__((ext_vector_type(4))) float f32x4;    // 4 fp32 acc

#define MDIM 2048
#define NDIM 4096

__device__ __forceinline__ ushort_t to_bf16(float f) {
    __hip_bfloat16 h = __float2bfloat16(f);
    return *reinterpret_cast<ushort_t*>(&h);
}

// ---------------- prep: fp32 -> bf16 cast ----------------
__global__ void cast_bf16_kernel(const float* __restrict__ in, ushort_t* __restrict__ out, int n) {
    int i = blockIdx.x * blockDim.x + threadIdx.x;
    if (i < n) out[i] = to_bf16(in[i]);
}

// ---------------- prep: W[K][N] fp32 -> WT[N][K] bf16 ----------------
__global__ void transpose_cast_kernel(const float* __restrict__ W, ushort_t* __restrict__ WT,
                                      int K, int N) {
    __shared__ float tile[32][33];
    const int tx = threadIdx.x, ty = threadIdx.y;  // (32, 8)
    const int n0 = blockIdx.x * 32, k0 = blockIdx.y * 32;
#pragma unroll
    for (int r = 0; r < 4; ++r)
        tile[ty + r * 8][tx] = W[(size_t)(k0 + ty + r * 8) * N + n0 + tx];
    __syncthreads();
    const int t = ty * 32 + tx;
    const int nl = t >> 3;          // 0..31 : local n
    const int kc = (t & 7) * 4;     // 0..28 : k chunk of 4
    ushort4 o;
    o.x = to_bf16(tile[kc + 0][nl]);
    o.y = to_bf16(tile[kc + 1][nl]);
    o.z = to_bf16(tile[kc + 2][nl]);
    o.w = to_bf16(tile[kc + 3][nl]);
    *reinterpret_cast<ushort4*>(&WT[(size_t)(n0 + nl) * K + k0 + kc]) = o;
}

// ---------------- GEMM v4: single region per K-tile, one barrier ----------------
// C[M][N] = act(A[M][K] @ BT[N][K]^T + bias)
// BM=128, BN=256, BK=64, 8 waves (2Mx4N), wave tile 64x64 (4x4 frags of 16x16x32).
// Grid (N/256, M/128) = 16x16 = 256 blocks = 1 block/CU.
// v3 post-mortem: per-tile cycle model (LDS serve 1536 + MFMA 1240 + 2x340
// barrier cost ~= measured 3150) shows the 4 barriers/tile force lockstep:
// LDS-read bursts and MFMA regions serialize. With 3-deep buffering the only
// hazards are cross-tile, so v4 keeps ONE vmcnt(6)+barrier per K-tile and puts
// all 16 ds_reads + 32 MFMAs in a single barrier-free region. The compiler's
// fine-grained counted lgkmcnt (verified m97 asm) interleaves kk=1 reads under
// kk=0 MFMAs, and waves slip phase -> LDS serve overlaps MFMA across waves.
// Source order reads -> GLDs -> MFMAs (no store-above-load alias stalls).
// Buffer-rotation safety: writes go to nb=(tt+2)%3, whose last readers
// finished before the PREVIOUS tile's barrier; reads of buf(tt+1) are gated by
// this tile's vmcnt(6) (own 6 GLDs of tt+2 outstanding => tt+1's drained) +
// barrier (makes all waves' writes visible). MFMA order per-acc unchanged
// -> numerics bitwise identical.

#define GLD(gp, lp) __builtin_amdgcn_global_load_lds(                      \
        (const __attribute__((address_space(1))) void*)(gp),               \
        (__attribute__((address_space(3))) void*)(lp), 16, 0, 0)

#define MFMA(d, a, b) d = __builtin_amdgcn_mfma_f32_16x16x32_bf16(a, b, d, 0, 0, 0)

template <typename OutT, bool RELU>
__global__ __launch_bounds__(512, 2) void gemm_p8(const ushort_t* __restrict__ A,
                                                  const ushort_t* __restrict__ BT,
                                                  const float* __restrict__ bias,
                                                  OutT* __restrict__ C, int Kdim) {
    __shared__ __align__(16) ushort_t As[3][128 * 64];   // 48 KB
    __shared__ __align__(16) ushort_t Bs[3][256 * 64];   // 96 KB

    const int t = threadIdx.x;
    const int l = t & 63;
    const int w = t >> 6;          // wave 0..7
    const int l16 = l & 15;
    const int quad = l >> 4;
    const int wr = w >> 2;         // 0..1  (M)
    const int wc = w & 3;          // 0..3  (N)
    const int m0 = blockIdx.y * 128;
    const int n0 = blockIdx.x * 256;

    f32x4 acc[4][4];
#pragma unroll
    for (int i = 0; i < 4; ++i)
#pragma unroll
        for (int j = 0; j < 4; ++j) acc[i][j] = (f32x4){0.f, 0.f, 0.f, 0.f};

    // --- staging addressing ---
    // wave w stages rows [g*64 + w*8, +8) of each 64-row group g; lane l -> row +l>>3,
    // LDS chunk l&7 (linear dest = base + l*16B). Source chunk is inverse-swizzled.
    const int srow = w * 8 + (l >> 3);
    const int scol = ((l & 7) ^ (l >> 3)) * 8;   // swizzled 16B chunk within the K-tile
    const ushort_t* gA0 = A  + (size_t)(m0 + srow) * Kdim + scol;
    const ushort_t* gA1 = A  + (size_t)(m0 + 64 + srow) * Kdim + scol;
    const ushort_t* gB0 = BT + (size_t)(n0 + srow) * Kdim + scol;
    const ushort_t* gB1 = BT + (size_t)(n0 + 64 + srow) * Kdim + scol;
    const ushort_t* gB2 = BT + (size_t)(n0 + 128 + srow) * Kdim + scol;
    const ushort_t* gB3 = BT + (size_t)(n0 + 192 + srow) * Kdim + scol;
    const int ldsW = w * 8 * 64;   // wave-uniform element offset of this wave's 8 rows

    // fragment reads: row = (wtile + i*16 + l16), chunk slot = (kk*4+quad)^(row&7)
    const int swz = l16 & 7;       // == row&7 for all our fragment rows
#define LDA_(base, i, kk) (*(const bf16x8*)&(base)[(wr * 64 + (i) * 16 + l16) * 64 + ((((kk) * 4 + quad) ^ swz) * 8)])
#define LDB_(base, j, kk) (*(const bf16x8*)&(base)[(wc * 64 + (j) * 16 + l16) * 64 + ((((kk) * 4 + quad) ^ swz) * 8)])

#define STAGE_TILE(buf, koff) do {                      \
        GLD(gA0 + (koff), &As[buf][ldsW]);              \
        GLD(gA1 + (koff), &As[buf][ldsW + 64 * 64]);    \
        GLD(gB0 + (koff), &Bs[buf][ldsW]);              \
        GLD(gB1 + (koff), &Bs[buf][ldsW + 64 * 64]);    \
        GLD(gB2 + (koff), &Bs[buf][ldsW + 128 * 64]);   \
        GLD(gB3 + (koff), &Bs[buf][ldsW + 192 * 64]);   \
    } while (0)

    // 16 MFMAs at one kk (i-major, j-minor -> per-acc order identical to prior versions)
#define MFMA16(a0, a1, a2, a3, b0, b1, b2, b3)                     \
        MFMA(acc[0][0], a0, b0); MFMA(acc[0][1], a0, b1);          \
        MFMA(acc[0][2], a0, b2); MFMA(acc[0][3], a0, b3);          \
        MFMA(acc[1][0], a1, b0); MFMA(acc[1][1], a1, b1);          \
        MFMA(acc[1][2], a1, b2); MFMA(acc[1][3], a1, b3);          \
        MFMA(acc[2][0], a2, b0); MFMA(acc[2][1], a2, b1);          \
        MFMA(acc[2][2], a2, b2); MFMA(acc[2][3], a2, b3);          \
        MFMA(acc[3][0], a3, b0); MFMA(acc[3][1], a3, b1);          \
        MFMA(acc[3][2], a3, b2); MFMA(acc[3][3], a3, b3)

    const int nt = Kdim >> 6;      // K-tiles of 64 (nt >= 2 for K in {256, 4096})

    // prologue: stage tiles 0 and 1; wait tile 0 (6 newer outstanding), sync.
    STAGE_TILE(0, 0);
    STAGE_TILE(1, 64);
    asm volatile("s_waitcnt vmcnt(6)" ::: "memory");
    __builtin_amdgcn_s_barrier();

    for (int tt = 0; tt < nt; ++tt) {
        const int buf = tt % 3;
        const int nb = (tt + 2) % 3;
        const int koff = (tt + 2) << 6;
        const bool more = (tt + 2) < nt;

        const ushort_t* __restrict__ Ab = &As[buf][0];
        const ushort_t* __restrict__ Bb = &Bs[buf][0];

        // all 16 fragment reads of this K-tile (compiler issues these and uses
        // counted lgkmcnt before the dependent MFMAs)
        bf16x8 a00 = LDA_(Ab, 0, 0), a01 = LDA_(Ab, 1, 0), a02 = LDA_(Ab, 2, 0), a03 = LDA_(Ab, 3, 0);
        bf16x8 b00 = LDB_(Bb, 0, 0), b01 = LDB_(Bb, 1, 0), b02 = LDB_(Bb, 2, 0), b03 = LDB_(Bb, 3, 0);
        bf16x8 a10 = LDA_(Ab, 0, 1), a11 = LDA_(Ab, 1, 1), a12 = LDA_(Ab, 2, 1), a13 = LDA_(Ab, 3, 1);
        bf16x8 b10 = LDB_(Bb, 0, 1), b11 = LDB_(Bb, 1, 1), b12 = LDB_(Bb, 2, 1), b13 = LDB_(Bb, 3, 1);

        // stage tile tt+2 (in flight for ~2 tile-times; waited via counted vmcnt)
        if (more) STAGE_TILE(nb, koff);

        // 32 MFMAs, single barrier-free region
        MFMA16(a00, a01, a02, a03, b00, b01, b02, b03);
        MFMA16(a10, a11, a12, a13, b10, b11, b12, b13);

        if (tt + 1 < nt) {
            // next iter reads buf (tt+1)%3: its 6 loads (all waves) must be done.
            // Own newer in flight = tile tt+2's 6 iff staged -> vmcnt(6), else drain.
            if (more) asm volatile("s_waitcnt vmcnt(6)" ::: "memory");
            else      asm volatile("s_waitcnt vmcnt(0)" ::: "memory");
            __builtin_amdgcn_s_barrier();
        }
    }

    // epilogue: C/D layout col=lane&15, row=quad*4+reg (unchanged mapping)
#pragma unroll
    for (int i = 0; i < 4; ++i) {
#pragma unroll
        for (int r = 0; r < 4; ++r) {
            const int grow = m0 + wr * 64 + i * 16 + quad * 4 + r;
#pragma unroll
            for (int j = 0; j < 4; ++j) {
                const int gcol = n0 + wc * 64 + j * 16 + l16;
                float v = acc[i][j][r] + bias[gcol];
                if (RELU) v = fmaxf(v, 0.0f);
                if constexpr (sizeof(OutT) == 2) {
                    C[(size_t)grow * NDIM + gcol] = to_bf16(v);
                } else {
                    C[(size_t)grow * NDIM + gcol] = v;
                }
            }
        }
    }
}

// ---------------- Sinkhorn, factored: P = diag(a) K diag(b) ----------------
// (unchanged — register-resident K, readlane broadcast)
__device__ __forceinline__ float rdl(float v, int l) {
    return __uint_as_float(__builtin_amdgcn_readlane(__float_as_uint(v), l));
}

__global__ __launch_bounds__(64) void sinkhorn_kernel(float* __restrict__ PM) {
    __shared__ __align__(16) float T[64 * 65];  // one-time transpose staging
    const int l = threadIdx.x;
    float* base = PM + (size_t)blockIdx.x * 4096;

    float Kcol[64];  // Kcol[r] = K[r][l]  (column l)
    float Krow[64];  // Krow[c] = K[l][c]  (row l)
#pragma unroll
    for (int r = 0; r < 64; ++r)
        Kcol[r] = __expf(-base[r * 64 + l]);
#pragma unroll
    for (int r = 0; r < 64; ++r)
        T[r * 65 + l] = Kcol[r];
    __syncthreads();
#pragma unroll
    for (int c = 0; c < 64; ++c)
        Krow[c] = T[l * 65 + c];

    float a = 0.0f, b = 1.0f;
    for (int it = 0; it < 1000; ++it) {
        float t1 = 0.0f;  // (K b)_row=l
#pragma unroll
        for (int c = 0; c < 64; ++c)
            t1 = fmaf(Krow[c], rdl(b, c), t1);
        a = 0.015625f / t1;  // r = 1/64

        float t2 = 0.0f;  // (K^T a)_col=l
#pragma unroll
        for (int r = 0; r < 64; ++r)
            t2 = fmaf(Kcol[r], rdl(a, r), t2);
        const float err = fabsf(b * t2 - 0.015625f);
        if (__ballot(err > 1e-6f) == 0ull) break;
        b = 0.015625f / t2;
    }

#pragma unroll
    for (int r = 0; r < 64; ++r)
        base[r * 64 + l] = rdl(a, r) * Kcol[r] * b;
}

extern "C" void kernel_launch(void* const* d_in, const int* in_sizes, int n_in,
                              void* d_out, int out_size, void* d_ws, size_t ws_size,
                              hipStream_t stream) {
    const float* z  = (const float*)d_in[0];
    const float* W1 = (const float*)d_in[1];
    const float* b1 = (const float*)d_in[2];
    const float* W2 = (const float*)d_in[3];
    const float* b2 = (const float*)d_in[4];
    const float* W3 = (const float*)d_in[5];
    const float* b3 = (const float*)d_in[6];
    float* out = (float*)d_out;
    char* ws = (char*)d_ws;

    // workspace layout (bytes)
    ushort_t* W2T = (ushort_t*)(ws + 0);                       // 4096*4096*2 = 32 MB
    ushort_t* W3T = (ushort_t*)(ws + (size_t)33554432);        // 32 MB
    ushort_t* C1b = (ushort_t*)(ws + (size_t)67108864);        // 2048*4096*2 = 16 MB
    ushort_t* C2b = (ushort_t*)(ws + (size_t)83886080);        // 16 MB
    ushort_t* Zb  = (ushort_t*)(ws + (size_t)100663296);       // 2048*256*2 = 1 MB
    ushort_t* W1T = (ushort_t*)(ws + (size_t)101711872);       // 4096*256*2 = 2 MB

    // prep
    cast_bf16_kernel<<<2048, 256, 0, stream>>>(z, Zb, MDIM * 256);
    transpose_cast_kernel<<<dim3(128, 8), dim3(32, 8), 0, stream>>>(W1, W1T, 256, 4096);
    transpose_cast_kernel<<<dim3(128, 128), dim3(32, 8), 0, stream>>>(W2, W2T, 4096, 4096);
    transpose_cast_kernel<<<dim3(128, 128), dim3(32, 8), 0, stream>>>(W3, W3T, 4096, 4096);

    // 3-layer MLP (bf16 MFMA, fp32 accum); layer 3 writes fp32 cost matrix into d_out
    gemm_p8<ushort_t, true><<<dim3(NDIM / 256, MDIM / 128), 512, 0, stream>>>(Zb, W1T, b1, C1b, 256);
    gemm_p8<ushort_t, true><<<dim3(NDIM / 256, MDIM / 128), 512, 0, stream>>>(C1b, W2T, b2, C2b, 4096);
    gemm_p8<float, false><<<dim3(NDIM / 256, MDIM / 128), 512, 0, stream>>>(C2b, W3T, b3, out, 4096);

    // Sinkhorn in-place on d_out (one wave per matrix, register-resident K)
    sinkhorn_kernel<<<2048, 64, 0, stream>>>(out);
}